// Round 6
// baseline (422.206 us; speedup 1.0000x reference)
//
#include <hip/hip_runtime.h>
#include <stdint.h>

// LSTMCell: B=8192, I=H=1024, fp32 in/out.
// Round 6: (1) main GEMM moved to mfma_f32_32x32x16_bf16 (2495 vs 2075 TF
// shape ceiling: MFMA-pipe term -17%, issue count halved) on the round-5
// read-ahead 3-barrier skeleton (LDS layout/staging/swizzle/vmcnt
// unchanged); epilogue restores 4-gate locality via shfl_xor(16) pair
// exchange + predicated pair-split writes. (2) prepass rewritten
// branch-free block-partitioned with 8-deep ILP (probing the ~170us
// unprofiled non-main time).
#define BATCH 8192
#define HD    1024
#define NT    32      // K-tiles of 64: 16 for X*Wx^T + 16 for H*Wh^T
// fallback kernel geometry (unchanged, proven)
#define BM    128
#define BNH   32
#define BK    32

typedef __bf16 bf16;
typedef __bf16 bf16x8  __attribute__((ext_vector_type(8)));
typedef __bf16 bf16x4  __attribute__((ext_vector_type(4)));
typedef float  f32x4   __attribute__((ext_vector_type(4)));
typedef float  f32x16  __attribute__((ext_vector_type(16)));

__device__ __forceinline__ float sigm(float x) {
    return 1.0f / (1.0f + __expf(-x));
}
__device__ __forceinline__ float tanh_f(float x) {
    return 1.0f - 2.0f / (__expf(2.0f * x) + 1.0f);
}
__device__ __forceinline__ bf16x4 cvt4(float4 v) {
    bf16x4 r;
    r[0] = (bf16)v.x; r[1] = (bf16)v.y; r[2] = (bf16)v.z; r[3] = (bf16)v.w;
    return r;
}
__device__ __forceinline__ bf16x8 cvt8(float4 a, float4 b) {
    bf16x8 r;
    r[0] = (bf16)a.x; r[1] = (bf16)a.y; r[2] = (bf16)a.z; r[3] = (bf16)a.w;
    r[4] = (bf16)b.x; r[5] = (bf16)b.y; r[6] = (bf16)b.z; r[7] = (bf16)b.w;
    return r;
}
// async global->LDS, 16B/lane; LDS dest = wave-uniform base + lane*16.
__device__ __forceinline__ void async_ld16(const void* g, void* l) {
    __builtin_amdgcn_global_load_lds(
        (const __attribute__((address_space(1))) uint32_t*)g,
        (__attribute__((address_space(3))) uint32_t*)l,
        16, 0, 0);
}

// ---- prepass: branch-free block partition, 8 units/thread, ILP-16 --------
// dst bf16x8 units: X [0,1048576) H [..2097152) Wx [..2621440) Wh [..3145728)
__global__ __launch_bounds__(256) void cvt_prepass(
    const float4* __restrict__ X, const float4* __restrict__ H,
    const float4* __restrict__ Wx, const float4* __restrict__ Wh,
    bf16x8* __restrict__ ws)
{
    const int bid = blockIdx.x;
    const int tid = threadIdx.x;
    const float4* s; size_t lb, dbase;
    if (bid < 512)       { s = X;  lb = bid;         dbase = 0u; }
    else if (bid < 1024) { s = H;  lb = bid - 512;   dbase = 1048576u; }
    else if (bid < 1280) { s = Wx; lb = bid - 1024;  dbase = 2097152u; }
    else                 { s = Wh; lb = bid - 1280;  dbase = 2621440u; }
    const size_t j0 = lb * 2048 + tid;
#pragma unroll
    for (int i = 0; i < 8; ++i) {
        const size_t j = j0 + (size_t)i * 256;
        ws[dbase + j] = cvt8(s[2 * j], s[2 * j + 1]);
    }
}

// ---- main: 256x256 tile, BK=64, 8 waves, 32x32x16 MFMA, 3-barrier --------
// N=256 cols = 4 gates x 64 h, gate-interleaved: LDS B row r -> weight row
// n = ((r>>4)&3)*1024 + h0 + (r>>6)*16 + (r&15). Wave (wm,wn): 128x64.
// Frags: 4 m-frags(32r) x 2 n-frags(32c) x 4 k-frags(16k) = 32 MFMA/tile.
// A frag: lane&31 = row, k = (lane>>5)*8+j (verified 16x16 analog);
// C/D: col=lane&31, row=(reg&3)+8*(reg>>2)+4*(lane>>5) [m74/m101].
// Gate decode: acc[mi][ni] = gate (2*ni + (l31>>4)) of h = h0+wn*16+(l31&15);
// epilogue shfl_xor(16) exchanges the missing gate pair.
// LDS/staging/swizzle/vmcnt identical to round 5 (proven-correct skeleton).

#define BAR() __builtin_amdgcn_s_barrier()

#define STAGE_A(tn_, hf_, o0_, o1_) do {                                    \
    const char* s_ = ((tn_) < 16) ? XbC : HbC;                              \
    const int kt_ = ((tn_) & 15) << 7;                                      \
    char* d_ = lds + (((tn_) & 1) << 16) + (hf_) * 16384 + tid16;           \
    async_ld16(s_ + (o0_) + kt_, d_);                                       \
    async_ld16(s_ + (o1_) + kt_, d_ + 8192); } while (0)

#define STAGE_B(tn_, hf_, o0_, o1_) do {                                    \
    const char* s_ = ((tn_) < 16) ? WxC : WhC;                              \
    const int kt_ = ((tn_) & 15) << 7;                                      \
    char* d_ = lds + (((tn_) & 1) << 16) + 32768 + (hf_) * 16384 + tid16;   \
    async_ld16(s_ + (o0_) + kt_, d_);                                       \
    async_ld16(s_ + (o1_) + kt_, d_ + 8192); } while (0)

#define G32(mp_, ni_) do {                                                  \
    _Pragma("unroll")                                                       \
    for (int mi2_ = 0; mi2_ < 2; ++mi2_) {                                  \
        _Pragma("unroll")                                                   \
        for (int kf_ = 0; kf_ < 4; ++kf_) {                                 \
            acc[(mp_)*2 + mi2_][ni_] =                                      \
                __builtin_amdgcn_mfma_f32_32x32x16_bf16(aF[mi2_][kf_],      \
                    bF[ni_][kf_], acc[(mp_)*2 + mi2_][ni_], 0, 0, 0);       \
        } } } while (0)

#define LDA32(mp_, LA_) do {                                                \
    _Pragma("unroll")                                                       \
    for (int mi2_ = 0; mi2_ < 2; ++mi2_)                                    \
        _Pragma("unroll")                                                   \
        for (int kf_ = 0; kf_ < 4; ++kf_)                                   \
            aF[mi2_][kf_] = *(const bf16x8*)((LA_) +                        \
                ((mp_)*2 + mi2_) * 4096 + cswz[kf_]); } while (0)

#define LDB32(ni_, LB_) do {                                                \
    _Pragma("unroll")                                                       \
    for (int kf_ = 0; kf_ < 4; ++kf_)                                       \
        bF[ni_][kf_] = *(const bf16x8*)((LB_) +                             \
            (ni_) * 4096 + cswz[kf_]); } while (0)

__global__ __launch_bounds__(512, 2) void lstm_mfma32(
    const bf16* __restrict__ Xb, const bf16* __restrict__ Hb,
    const bf16* __restrict__ Wxb, const bf16* __restrict__ Whb,
    const float* __restrict__ C, const float* __restrict__ bx,
    const float* __restrict__ bh, float* __restrict__ out)
{
    __shared__ __align__(16) char lds[131072];

    const int tid  = threadIdx.x;
    const int lane = tid & 63;
    const int w    = tid >> 6;
    const int wm   = w >> 2;            // M half 0/1
    const int wn   = w & 3;             // N quarter 0..3
    const int l31  = lane & 31;
    const int l32  = lane >> 5;

    // XCD k owns M-tiles {4k..4k+3} x all 16 N-cols (N-minor), bijective.
    const int bid = blockIdx.x;
    const int k8  = bid & 7;
    const int j   = bid >> 3;
    const int mi_t = (k8 << 2) | (j & 3);
    const int col  = j >> 2;
    const int m0  = mi_t << 8;
    const int h0  = col << 6;

    // ---- staging addresses (pre-swizzled global source, linear LDS dest) --
    const int tid16 = tid << 4;
    const int R0    = tid >> 3;
    const uint32_t swc = ((tid & 7) ^ (R0 & 7)) << 4;
    const char* XbC = (const char*)Xb;
    const char* HbC = (const char*)Hb;
    const char* WxC = (const char*)Wxb;
    const char* WhC = (const char*)Whb;
    const uint32_t a00 = ((uint32_t)(m0 + R0)       << 11) + swc;
    const uint32_t a01 = ((uint32_t)(m0 + R0 +  64) << 11) + swc;
    const uint32_t a10 = ((uint32_t)(m0 + R0 + 128) << 11) + swc;
    const uint32_t a11 = ((uint32_t)(m0 + R0 + 192) << 11) + swc;
#define NROW(r_) (((((r_) >> 4) & 3) << 10) + h0 + (((r_) >> 6) << 4) + ((r_) & 15))
    const uint32_t b00 = ((uint32_t)NROW(R0)       << 11) + swc;
    const uint32_t b01 = ((uint32_t)NROW(R0 +  64) << 11) + swc;
    const uint32_t b10 = ((uint32_t)NROW(R0 + 128) << 11) + swc;
    const uint32_t b11 = ((uint32_t)NROW(R0 + 192) << 11) + swc;
#undef NROW

    // ---- ds_read bases: row = (wm*128|wn*64) + frag*32 + l31, 128B rows ---
    const int baseA_l = (wm * 128 + l31) * 128;
    const int baseB_l = 32768 + (wn * 64 + l31) * 128;
    int cswz[4];
#pragma unroll
    for (int kf = 0; kf < 4; ++kf)
        cswz[kf] = ((kf * 2 + l32) ^ (l31 & 7)) << 4;

    f32x16 acc[4][2];
#pragma unroll
    for (int i = 0; i < 4; ++i)
#pragma unroll
        for (int n = 0; n < 2; ++n)
#pragma unroll
            for (int r = 0; r < 16; ++r) acc[i][n][r] = 0.f;

    // ---- prologue: A(0), B(0), B(1), A(1)-lo; drain tile0, leave 6 --------
    STAGE_A(0, 0, a00, a01);
    STAGE_A(0, 1, a10, a11);
    STAGE_B(0, 0, b00, b01);
    STAGE_B(0, 1, b10, b11);
    STAGE_B(1, 0, b00, b01);
    STAGE_B(1, 1, b10, b11);
    STAGE_A(1, 0, a00, a01);
    asm volatile("s_waitcnt vmcnt(6)" ::: "memory");
    BAR();

    bf16x8 aF[2][4], bF[2][4];
    // initial tile-0 reads: aF = m-frags 0-1, bF[0] = n-frag 0
    {
        const char* LA0 = lds + baseA_l;
        const char* LB0 = lds + baseB_l;
        LDA32(0, LA0);
        LDB32(0, LB0);
    }

#pragma unroll 1
    for (int t = 0; t < NT; ++t) {
        const char* LA  = lds + ((t & 1) << 16) + baseA_l;
        const char* LB  = lds + ((t & 1) << 16) + baseB_l;
        const char* LAn = lds + (((t + 1) & 1) << 16) + baseA_l;
        const char* LBn = lds + (((t + 1) & 1) << 16) + baseB_l;

        if (t + 1 < NT) STAGE_A(t + 1, 1, a10, a11);
        LDB32(1, LB);                      // bF[1](t), hidden under G(0,0)
        __builtin_amdgcn_s_setprio(1);
        G32(0, 0);                         // m-frags 0-1 x n-frag 0
        __builtin_amdgcn_s_setprio(0);
        __builtin_amdgcn_s_setprio(1);
        G32(0, 1);                         // m-frags 0-1 x n-frag 1
        __builtin_amdgcn_s_setprio(0);
        LDA32(1, LA);                      // aF <- m-frags 2-3 (t)
        BAR();  // #1: all waves' B(t) + A(m01,t) reads complete
        if (t + 2 < NT) STAGE_B(t + 2, 0, b00, b01);
        __builtin_amdgcn_s_setprio(1);
        G32(1, 1);                         // m-frags 2-3 x n-frag 1
        __builtin_amdgcn_s_setprio(0);
        BAR();  // #2: all waves' A(m23,t) reads complete -> stages safe
        if (t + 2 < NT) {
            STAGE_B(t + 2, 1, b10, b11);
            STAGE_A(t + 2, 0, a00, a01);
            asm volatile("s_waitcnt vmcnt(6)" ::: "memory");
        } else if (t == NT - 2) {
            asm volatile("s_waitcnt vmcnt(0)" ::: "memory");
        }
        BAR();  // #3: buf(t+1) visible
        __builtin_amdgcn_s_setprio(1);
        G32(1, 0);                         // m-frags 2-3 x n-frag 0
        __builtin_amdgcn_s_setprio(0);
        if (t + 1 < NT) {                  // trailing reads for t+1
            LDA32(0, LAn);
            LDB32(0, LBn);
        }
    }

    // ---- fused LSTM epilogue with gate-pair exchange ----------------------
    // lane holds gates {0,2} (l31<16) or {1,3} (l31>=16) of its h;
    // shfl_xor(16) supplies the other pair; pair-split predicated writes.
    const int h    = h0 + wn * 16 + (l31 & 15);
    const int hi16 = (l31 >> 4) & 1;
    float bias[4];
#pragma unroll
    for (int g = 0; g < 4; ++g) bias[g] = bx[g * HD + h] + bh[g * HD + h];
    const size_t BH = (size_t)BATCH * HD;
    const int mbase = m0 + wm * 128;
#pragma unroll
    for (int mi = 0; mi < 4; ++mi) {
#pragma unroll
        for (int r = 0; r < 16; ++r) {
            const float own0 = acc[mi][0][r];
            const float own1 = acc[mi][1][r];
            const float oth0 = __shfl_xor(own0, 16, 64);
            const float oth1 = __shfl_xor(own1, 16, 64);
            const float gi = hi16 ? oth0 : own0;
            const float gf = hi16 ? own0 : oth0;
            const float gg = hi16 ? oth1 : own1;
            const float go = hi16 ? own1 : oth1;
            if (hi16 ? (r >= 8) : (r < 8)) {
                const int row = (r & 3) + ((r >> 2) << 3) + (l32 << 2);
                const int m = mbase + mi * 32 + row;
                const float ia = sigm(gi);
                const float fa = sigm(gf);
                const float ga = tanh_f(gg);
                const float oa = sigm(go);
                const size_t idx = (size_t)m * HD + h;
                const float nc = fmaf(fa, C[idx], ia * ga);
                const float nh = oa * tanh_f(nc);
                out[idx]          = nh;
                out[BH + idx]     = nh;
                out[2 * BH + idx] = nc;
            }
        }
    }
}

// ---- fallback (proven): fp32 loads + in-loop cvt, register staging --------
__global__ __launch_bounds__(256) void lstm_fused_f32(
    const float* __restrict__ X, const float* __restrict__ Hs,
    const float* __restrict__ C, const float* __restrict__ Wx,
    const float* __restrict__ Wh, const float* __restrict__ bx,
    const float* __restrict__ bh, float* __restrict__ out)
{
    __shared__ __align__(16) bf16 As[BM * BK];
    __shared__ __align__(16) bf16 Bs[BM * BK];
    const int tid = threadIdx.x, lane = tid & 63, w = tid >> 6;
    const int m0 = blockIdx.x * BM, h0 = blockIdx.y * BNH;
    f32x4 acc[2][8];
#pragma unroll
    for (int i = 0; i < 2; ++i)
#pragma unroll
        for (int j = 0; j < 8; ++j) acc[i][j] = (f32x4){0.f, 0.f, 0.f, 0.f};
    int arow[4], col4[4], bn[4];
#pragma unroll
    for (int j = 0; j < 4; ++j) {
        const int off = tid * 16 + j * 4096;
        arow[j] = off >> 7;
        col4[j] = (off & 127) >> 2;
        bn[j]   = ((arow[j] >> 5) << 10) + h0 + (arow[j] & 31);
    }
    const int quad = lane >> 4, c16 = lane & 15;
    float4 pA[4], pB[4];
    auto loadi = [&](int i) {
        const float* Ab = (i < 32) ? X : Hs;
        const float* Wb = (i < 32) ? Wx : Wh;
        const int kin = (i & 31) << 5;
#pragma unroll
        for (int j = 0; j < 4; ++j) {
            pA[j] = *(const float4*)(Ab + (size_t)(m0 + arow[j]) * HD + kin + col4[j]);
            pB[j] = *(const float4*)(Wb + (size_t)bn[j] * HD + kin + col4[j]);
        }
    };
    loadi(0);
#pragma unroll 1
    for (int i = 0; i < 64; ++i) {
        __syncthreads();
#pragma unroll
        for (int j = 0; j < 4; ++j) {
            *(bf16x4*)&As[arow[j] * BK + col4[j]] = cvt4(pA[j]);
            *(bf16x4*)&Bs[arow[j] * BK + col4[j]] = cvt4(pB[j]);
        }
        __syncthreads();
        if (i < 63) loadi(i + 1);
        bf16x8 a[2], b[8];
#pragma unroll
        for (int im = 0; im < 2; ++im)
            a[im] = *(const bf16x8*)((const char*)As + (w * 32 + im * 16 + c16) * 64 + quad * 16);
#pragma unroll
        for (int in = 0; in < 8; ++in)
            b[in] = *(const bf16x8*)((const char*)Bs + (in * 16 + c16) * 64 + quad * 16);
#pragma unroll
        for (int im = 0; im < 2; ++im)
#pragma unroll
            for (int in = 0; in < 8; ++in)
                acc[im][in] = __builtin_amdgcn_mfma_f32_16x16x32_bf16(
                    a[im], b[in], acc[im][in], 0, 0, 0);
    }
    float bias[2][4];
#pragma unroll
    for (int hs = 0; hs < 2; ++hs) {
        const int h = h0 + hs * 16 + c16;
#pragma unroll
        for (int g = 0; g < 4; ++g) bias[hs][g] = bx[g * HD + h] + bh[g * HD + h];
    }
    const size_t BH = (size_t)BATCH * HD;
#pragma unroll
    for (int im = 0; im < 2; ++im)
#pragma unroll
        for (int r = 0; r < 4; ++r) {
            const int m = m0 + w * 32 + im * 16 + quad * 4 + r;
#pragma unroll
            for (int hs = 0; hs < 2; ++hs) {
                const int h = h0 + hs * 16 + c16;
                const float gi = acc[im][hs + 0][r] + bias[hs][0];
                const float gf = acc[im][hs + 2][r] + bias[hs][1];
                const float gg = acc[im][hs + 4][r] + bias[hs][2];
                const float go = acc[im][hs + 6][r] + bias[hs][3];
                const float ia = sigm(gi), fa = sigm(gf);
                const float ga = tanh_f(gg), oa = sigm(go);
                const size_t idx = (size_t)m * HD + h;
                const float nc = fa * C[idx] + ia * ga;
                const float nh = oa * tanh_f(nc);
                out[idx] = nh; out[BH + idx] = nh; out[2 * BH + idx] = nc;
            }
        }
}

extern "C" void kernel_launch(void* const* d_in, const int* in_sizes, int n_in,
                              void* d_out, int out_size, void* d_ws, size_t ws_size,
                              hipStream_t stream) {
    const float* X  = (const float*)d_in[0];
    const float* Hs = (const float*)d_in[1];
    const float* C  = (const float*)d_in[2];
    const float* Wx = (const float*)d_in[3];
    const float* Wh = (const float*)d_in[4];
    const float* bx = (const float*)d_in[5];
    const float* bh = (const float*)d_in[6];
    float* out = (float*)d_out;

    const size_t need = 48ull << 20;  // Xb+Hb (32MB) + Wxb+Whb (16MB)
    if (ws_size >= need) {
        bf16* Xb  = (bf16*)d_ws;
        bf16* Hb  = Xb + (size_t)BATCH * HD;
        bf16* Wxb = Hb + (size_t)BATCH * HD;
        bf16* Whb = Wxb + (size_t)4 * HD * HD;
        cvt_prepass<<<1536, 256, 0, stream>>>(
            (const float4*)X, (const float4*)Hs,
            (const float4*)Wx, (const float4*)Wh, (bf16x8*)d_ws);
        lstm_mfma32<<<dim3(512), dim3(512), 0, stream>>>(
            Xb, Hb, Wxb, Whb, C, bx, bh, out);
    } else {
        dim3 grid(BATCH / BM, HD / BNH);
        lstm_fused_f32<<<grid, 256, 0, stream>>>(X, Hs, C, Wx, Wh, bx, bh, out);
    }
}

// Round 7
// 351.626 us; speedup vs baseline: 1.2007x; 1.2007x over previous
//
#include <hip/hip_runtime.h>
#include <stdint.h>

// LSTMCell: B=8192, I=H=1024, fp32 in/out.
// Round 7: (1) REVERT main to round-5 16x16 skeleton (round 6's 32x32 frag
// reads alias 4-way in the 8-slot XOR domain: conflicts 0->1.26e7, -50%).
// (2) Eliminate X/H prepass: A is reg-staged fp32->bf16 in-kernel
// (global_load_dwordx4 x8 -> cvt -> ds_write_b128 x4 to write-side-swizzled
// addrs); B keeps proven gload_lds + pre-swizzled source from a now tiny
// weights-only prepass. Probes whether the invariant ~165us non-main time
// was prepass or fixed harness overhead.
#define BATCH 8192
#define HD    1024
#define NT    32      // K-tiles of 64: 16 for X*Wx^T + 16 for H*Wh^T
// fallback kernel geometry (unchanged, proven)
#define BM    128
#define BNH   32
#define BK    32

typedef __bf16 bf16;
typedef __bf16 bf16x8  __attribute__((ext_vector_type(8)));
typedef __bf16 bf16x4  __attribute__((ext_vector_type(4)));
typedef float  f32x4   __attribute__((ext_vector_type(4)));

__device__ __forceinline__ float sigm(float x) {
    return 1.0f / (1.0f + __expf(-x));
}
__device__ __forceinline__ float tanh_f(float x) {
    return 1.0f - 2.0f / (__expf(2.0f * x) + 1.0f);
}
__device__ __forceinline__ bf16x4 cvt4(float4 v) {
    bf16x4 r;
    r[0] = (bf16)v.x; r[1] = (bf16)v.y; r[2] = (bf16)v.z; r[3] = (bf16)v.w;
    return r;
}
__device__ __forceinline__ bf16x8 cvt8(float4 a, float4 b) {
    bf16x8 r;
    r[0] = (bf16)a.x; r[1] = (bf16)a.y; r[2] = (bf16)a.z; r[3] = (bf16)a.w;
    r[4] = (bf16)b.x; r[5] = (bf16)b.y; r[6] = (bf16)b.z; r[7] = (bf16)b.w;
    return r;
}
// async global->LDS, 16B/lane; LDS dest = wave-uniform base + lane*16.
__device__ __forceinline__ void async_ld16(const void* g, void* l) {
    __builtin_amdgcn_global_load_lds(
        (const __attribute__((address_space(1))) uint32_t*)g,
        (__attribute__((address_space(3))) uint32_t*)l,
        16, 0, 0);
}

// ---- prepass: weights only, fp32 -> bf16 (32MB read / 16MB write) ---------
__global__ __launch_bounds__(256) void cvt_prepass_w(
    const float4* __restrict__ Wx, const float4* __restrict__ Wh,
    bf16x8* __restrict__ ws)
{
    const size_t NW = (size_t)4 * HD * HD / 8;   // 512K bf16x8 units each
    const size_t stride = (size_t)gridDim.x * blockDim.x;
    for (size_t p = (size_t)blockIdx.x * blockDim.x + threadIdx.x;
         p < 2 * NW; p += stride) {
        const float4* s = (p < NW) ? Wx : Wh;
        const size_t o  = (p < NW) ? p : p - NW;
        ws[p] = cvt8(s[2 * o], s[2 * o + 1]);
    }
}

// ---- main: 256x256 tile, BK=64, 8 waves, 16x16 MFMA, 3-barrier ------------
// N=256 cols = 4 gates x 64 h, gate-interleaved: LDS B row r -> weight row
// n = ((r>>4)&3)*1024 + h0 + (r>>6)*16 + (r&15). Wave (wm,wn): 128x64.
// LDS 128KB static: buf[2] x {A[256][128B], B[256][128B]} bf16, XOR-swizzle
// (slot ^= row&7). B: gload_lds with pre-swizzled SOURCE (linear dest).
// A: reg-staged from fp32 X/H -> cvt -> ds_write to swizzled DEST (same
// final layout). Queue: [B(t+1)x4 old][paA(t+1)x8][B(t+2)x4 new]; the
// compiler's auto-wait for pa (vmcnt<=4) also drains B(t+1); lgkm(0)+BAR3
// publishes the A ds_writes before the trailing reads.
// Barriers: #1 gates B-lo(t+2) stage (b-reads consumed at Q02 before it);
// #2 gates B-hi(t+2) (Q42's lgkm before it); #3 publishes buf(t+1).

#define BARM()  asm volatile("s_barrier" ::: "memory")
#define LGKM0() asm volatile("s_waitcnt lgkmcnt(0)" ::: "memory")

#define STAGE_B(tn_, hf_, o0_, o1_) do {                                    \
    const char* s_ = ((tn_) < 16) ? WxC : WhC;                              \
    const int kt_ = ((tn_) & 15) << 7;                                      \
    char* d_ = lds + (((tn_) & 1) << 16) + 32768 + (hf_) * 16384 + tid16;   \
    async_ld16(s_ + (o0_) + kt_, d_);                                       \
    async_ld16(s_ + (o1_) + kt_, d_ + 8192); } while (0)

// A fp32 loads: rows R0+q*64, cols (tn&15)*64 + (tid&7)*8 .. +8
#define LOAD_A(tn_) do {                                                    \
    const float* s_ = ((tn_) < 16) ? Xf : Hf;                               \
    const int kb_ = (((tn_) & 15) << 6) + ((tid & 7) << 3);                 \
    _Pragma("unroll")                                                       \
    for (int q_ = 0; q_ < 4; ++q_) {                                        \
        const float* r_ = s_ + (size_t)(m0 + R0 + (q_ << 6)) * HD + kb_;    \
        pa[q_][0] = *(const float4*)(r_);                                   \
        pa[q_][1] = *(const float4*)(r_ + 4);                               \
    } } while (0)

// A ds_writes: LDS[R0+q*64][slot=(tid&7)^(R0&7)] <- bf16 cvt of pa
#define WRITE_A(tn_) do {                                                   \
    char* d_ = lds + (((tn_) & 1) << 16) + R0 * 128 + aswz;                 \
    _Pragma("unroll")                                                       \
    for (int q_ = 0; q_ < 4; ++q_)                                          \
        *(bf16x8*)(d_ + (q_ << 13)) = cvt8(pa[q_][0], pa[q_][1]);           \
    } while (0)

#define MFMA_Q(IMB_, INB_)                                                  \
    _Pragma("unroll")                                                       \
    for (int im_ = 0; im_ < 4; ++im_) {                                     \
        _Pragma("unroll")                                                   \
        for (int in_ = 0; in_ < 2; ++in_) {                                 \
            acc[im_ + IMB_][in_ + INB_] =                                   \
                __builtin_amdgcn_mfma_f32_16x16x32_bf16(aF[im_][0],         \
                    bF[in_ + INB_][0], acc[im_ + IMB_][in_ + INB_], 0,0,0); \
            acc[im_ + IMB_][in_ + INB_] =                                   \
                __builtin_amdgcn_mfma_f32_16x16x32_bf16(aF[im_][1],         \
                    bF[in_ + INB_][1], acc[im_ + IMB_][in_ + INB_], 0,0,0); \
        }                                                                   \
    }

__global__ __launch_bounds__(512, 2) void lstm_mfma8(
    const float* __restrict__ Xf, const float* __restrict__ Hf,
    const bf16* __restrict__ Wxb, const bf16* __restrict__ Whb,
    const float* __restrict__ C, const float* __restrict__ bx,
    const float* __restrict__ bh, float* __restrict__ out)
{
    __shared__ __align__(16) char lds[131072];

    const int tid  = threadIdx.x;
    const int lane = tid & 63;
    const int w    = tid >> 6;
    const int wm   = w >> 2;            // M half 0/1
    const int wn   = w & 3;             // N quarter 0..3
    const int quad = lane >> 4;
    const int c16  = lane & 15;

    // XCD k owns M-tiles {4k..4k+3} x all 16 N-cols (N-minor), bijective.
    const int bid = blockIdx.x;
    const int k8  = bid & 7;
    const int j   = bid >> 3;
    const int mi  = (k8 << 2) | (j & 3);
    const int col = j >> 2;
    const int m0  = mi << 8;
    const int h0  = col << 6;

    // ---- B staging (pre-swizzled global source, linear LDS dest) ----------
    const int tid16 = tid << 4;
    const int R0    = tid >> 3;                       // row-in-64 group
    const uint32_t swc = ((tid & 7) ^ (R0 & 7)) << 4;
    const int aswz = ((tid & 7) ^ (R0 & 7)) << 4;     // A write-side swizzle
    const char* WxC = (const char*)Wxb;
    const char* WhC = (const char*)Whb;
#define NROW(r_) (((((r_) >> 4) & 3) << 10) + h0 + (((r_) >> 6) << 4) + ((r_) & 15))
    const uint32_t b00 = ((uint32_t)NROW(R0)       << 11) + swc;
    const uint32_t b01 = ((uint32_t)NROW(R0 +  64) << 11) + swc;
    const uint32_t b10 = ((uint32_t)NROW(R0 + 128) << 11) + swc;
    const uint32_t b11 = ((uint32_t)NROW(R0 + 192) << 11) + swc;
#undef NROW

    // ---- ds_read bases (swizzled col16: row&7 == c16&7 for all frags) -----
    const int baseA = (wm * 128 + c16) * 128;
    const int baseB = 32768 + (wn * 64 + c16) * 128;
    const int sw0 = ((quad    ) ^ (c16 & 7)) << 4;
    const int sw1 = ((quad + 4) ^ (c16 & 7)) << 4;

    f32x4 acc[8][4];
#pragma unroll
    for (int i = 0; i < 8; ++i)
#pragma unroll
        for (int j2 = 0; j2 < 4; ++j2) acc[i][j2] = (f32x4){0.f, 0.f, 0.f, 0.f};

    float4 pa[4][2];

    // ---- prologue: A(0) regs, B(0), B(1); write A(0); drain B(0) ----------
    LOAD_A(0);
    STAGE_B(0, 0, b00, b01);
    STAGE_B(0, 1, b10, b11);
    STAGE_B(1, 0, b00, b01);
    STAGE_B(1, 1, b10, b11);
    WRITE_A(0);   // compiler waits pa (vmcnt<=8)
    asm volatile("s_waitcnt vmcnt(4)" ::: "memory");  // B(0) in LDS
    LGKM0();      // A(0) ds_writes committed
    BARM();

    bf16x8 aF[4][2], bF[4][2];
    // initial tile-0 first-quad fragments (aF=im0-3, bF01)
    {
        const char* LA = lds + baseA;
        const char* LB = lds + baseB;
#pragma unroll
        for (int im = 0; im < 4; ++im) {
            aF[im][0] = *(const bf16x8*)(LA + im * 2048 + sw0);
            aF[im][1] = *(const bf16x8*)(LA + im * 2048 + sw1);
        }
#pragma unroll
        for (int in = 0; in < 2; ++in) {
            bF[in][0] = *(const bf16x8*)(LB + in * 2048 + sw0);
            bF[in][1] = *(const bf16x8*)(LB + in * 2048 + sw1);
        }
    }

#pragma unroll 1
    for (int t = 0; t < NT; ++t) {
        const char* LA  = lds + ((t & 1) << 16) + baseA;
        const char* LB  = lds + ((t & 1) << 16) + baseB;
        const char* LAn = lds + (((t + 1) & 1) << 16) + baseA;
        const char* LBn = lds + (((t + 1) & 1) << 16) + baseB;

        if (t + 1 < NT) LOAD_A(t + 1);     // 8 fp32 loads, in flight all tile
#pragma unroll
        for (int in = 2; in < 4; ++in) {   // bF23(t), hidden under Q00
            bF[in][0] = *(const bf16x8*)(LB + in * 2048 + sw0);
            bF[in][1] = *(const bf16x8*)(LB + in * 2048 + sw1);
        }
        __builtin_amdgcn_s_setprio(1);
        MFMA_Q(0, 0);
        __builtin_amdgcn_s_setprio(0);
        __builtin_amdgcn_s_setprio(1);
        MFMA_Q(0, 2);
        __builtin_amdgcn_s_setprio(0);
#pragma unroll
        for (int im = 0; im < 4; ++im) {   // aF <- im4-7 (t)
            aF[im][0] = *(const bf16x8*)(LA + (im + 4) * 2048 + sw0);
            aF[im][1] = *(const bf16x8*)(LA + (im + 4) * 2048 + sw1);
        }
        BARM();  // #1: B(t) reads consumed (Q00/Q02) -> B-lo(t+2) stage safe
        if (t + 2 < NT) STAGE_B(t + 2, 0, b00, b01);
        __builtin_amdgcn_s_setprio(1);
        MFMA_Q(4, 2);
        __builtin_amdgcn_s_setprio(0);
        BARM();  // #2: A(t)/B-hi(t) reads consumed -> stage + A-write safe
        if (t + 2 < NT) STAGE_B(t + 2, 1, b10, b11);
        if (t + 1 < NT) WRITE_A(t + 1);    // auto vmcnt<=4 drains B(t+1) too
        else asm volatile("s_waitcnt vmcnt(0)" ::: "memory");
        LGKM0();                           // A ds_writes committed
        BARM();  // #3: buf(t+1) fully visible
        __builtin_amdgcn_s_setprio(1);
        MFMA_Q(4, 0);
        __builtin_amdgcn_s_setprio(0);
        if (t + 1 < NT) {                  // trailing reads for t+1
#pragma unroll
            for (int im = 0; im < 4; ++im) {
                aF[im][0] = *(const bf16x8*)(LAn + im * 2048 + sw0);
                aF[im][1] = *(const bf16x8*)(LAn + im * 2048 + sw1);
            }
#pragma unroll
            for (int in = 0; in < 2; ++in) {
                bF[in][0] = *(const bf16x8*)(LBn + in * 2048 + sw0);
                bF[in][1] = *(const bf16x8*)(LBn + in * 2048 + sw1);
            }
        }
    }

    // ---- fused LSTM epilogue: lane holds all 4 gates of (m-range, h) ------
    const int h = h0 + wn * 16 + c16;
    float bias[4];
#pragma unroll
    for (int g = 0; g < 4; ++g) bias[g] = bx[g * HD + h] + bh[g * HD + h];
    const size_t BH = (size_t)BATCH * HD;
    const int mb = m0 + wm * 128 + quad * 4;
#pragma unroll
    for (int im = 0; im < 8; ++im) {
#pragma unroll
        for (int r = 0; r < 4; ++r) {
            const int m = mb + im * 16 + r;
            const float gi = acc[im][0][r] + bias[0];
            const float gf = acc[im][1][r] + bias[1];
            const float gg = acc[im][2][r] + bias[2];
            const float go = acc[im][3][r] + bias[3];
            const float ia = sigm(gi);
            const float fa = sigm(gf);
            const float ga = tanh_f(gg);
            const float oa = sigm(go);
            const size_t idx = (size_t)m * HD + h;
            const float nc = fmaf(fa, C[idx], ia * ga);
            const float nh = oa * tanh_f(nc);
            out[idx]          = nh;
            out[BH + idx]     = nh;
            out[2 * BH + idx] = nc;
        }
    }
}

// ---- fallback (proven): fp32 loads + in-loop cvt, register staging --------
__global__ __launch_bounds__(256) void lstm_fused_f32(
    const float* __restrict__ X, const float* __restrict__ Hs,
    const float* __restrict__ C, const float* __restrict__ Wx,
    const float* __restrict__ Wh, const float* __restrict__ bx,
    const float* __restrict__ bh, float* __restrict__ out)
{
    __shared__ __align__(16) bf16 As[BM * BK];
    __shared__ __align__(16) bf16 Bs[BM * BK];
    const int tid = threadIdx.x, lane = tid & 63, w = tid >> 6;
    const int m0 = blockIdx.x * BM, h0 = blockIdx.y * BNH;
    f32x4 acc[2][8];
#pragma unroll
    for (int i = 0; i < 2; ++i)
#pragma unroll
        for (int j = 0; j < 8; ++j) acc[i][j] = (f32x4){0.f, 0.f, 0.f, 0.f};
    int arow[4], col4[4], bn[4];
#pragma unroll
    for (int j = 0; j < 4; ++j) {
        const int off = tid * 16 + j * 4096;
        arow[j] = off >> 7;
        col4[j] = (off & 127) >> 2;
        bn[j]   = ((arow[j] >> 5) << 10) + h0 + (arow[j] & 31);
    }
    const int quad = lane >> 4, c16 = lane & 15;
    float4 pA[4], pB[4];
    auto loadi = [&](int i) {
        const float* Ab = (i < 32) ? X : Hs;
        const float* Wb = (i < 32) ? Wx : Wh;
        const int kin = (i & 31) << 5;
#pragma unroll
        for (int j = 0; j < 4; ++j) {
            pA[j] = *(const float4*)(Ab + (size_t)(m0 + arow[j]) * HD + kin + col4[j]);
            pB[j] = *(const float4*)(Wb + (size_t)bn[j] * HD + kin + col4[j]);
        }
    };
    loadi(0);
#pragma unroll 1
    for (int i = 0; i < 64; ++i) {
        __syncthreads();
#pragma unroll
        for (int j = 0; j < 4; ++j) {
            *(bf16x4*)&As[arow[j] * BK + col4[j]] = cvt4(pA[j]);
            *(bf16x4*)&Bs[arow[j] * BK + col4[j]] = cvt4(pB[j]);
        }
        __syncthreads();
        if (i < 63) loadi(i + 1);
        bf16x8 a[2], b[8];
#pragma unroll
        for (int im = 0; im < 2; ++im)
            a[im] = *(const bf16x8*)((const char*)As + (w * 32 + im * 16 + c16) * 64 + quad * 16);
#pragma unroll
        for (int in = 0; in < 8; ++in)
            b[in] = *(const bf16x8*)((const char*)Bs + (in * 16 + c16) * 64 + quad * 16);
#pragma unroll
        for (int im = 0; im < 2; ++im)
#pragma unroll
            for (int in = 0; in < 8; ++in)
                acc[im][in] = __builtin_amdgcn_mfma_f32_16x16x32_bf16(
                    a[im], b[in], acc[im][in], 0, 0, 0);
    }
    float bias[2][4];
#pragma unroll
    for (int hs = 0; hs < 2; ++hs) {
        const int h = h0 + hs * 16 + c16;
#pragma unroll
        for (int g = 0; g < 4; ++g) bias[hs][g] = bx[g * HD + h] + bh[g * HD + h];
    }
    const size_t BH = (size_t)BATCH * HD;
#pragma unroll
    for (int im = 0; im < 2; ++im)
#pragma unroll
        for (int r = 0; r < 4; ++r) {
            const int m = m0 + w * 32 + im * 16 + quad * 4 + r;
#pragma unroll
            for (int hs = 0; hs < 2; ++hs) {
                const int h = h0 + hs * 16 + c16;
                const float gi = acc[im][hs + 0][r] + bias[hs][0];
                const float gf = acc[im][hs + 2][r] + bias[hs][1];
                const float gg = acc[im][hs + 4][r] + bias[hs][2];
                const float go = acc[im][hs + 6][r] + bias[hs][3];
                const float ia = sigm(gi), fa = sigm(gf);
                const float ga = tanh_f(gg), oa = sigm(go);
                const size_t idx = (size_t)m * HD + h;
                const float nc = fa * C[idx] + ia * ga;
                const float nh = oa * tanh_f(nc);
                out[idx] = nh; out[BH + idx] = nh; out[2 * BH + idx] = nc;
            }
        }
}

extern "C" void kernel_launch(void* const* d_in, const int* in_sizes, int n_in,
                              void* d_out, int out_size, void* d_ws, size_t ws_size,
                              hipStream_t stream) {
    const float* X  = (const float*)d_in[0];
    const float* Hs = (const float*)d_in[1];
    const float* C  = (const float*)d_in[2];
    const float* Wx = (const float*)d_in[3];
    const float* Wh = (const float*)d_in[4];
    const float* bx = (const float*)d_in[5];
    const float* bh = (const float*)d_in[6];
    float* out = (float*)d_out;

    const size_t need = 16ull << 20;  // Wxb+Whb only
    if (ws_size >= need) {
        bf16* Wxb = (bf16*)d_ws;
        bf16* Whb = Wxb + (size_t)4 * HD * HD;
        cvt_prepass_w<<<2048, 256, 0, stream>>>(
            (const float4*)Wx, (const float4*)Wh, (bf16x8*)d_ws);
        lstm_mfma8<<<dim3(512), dim3(512), 0, stream>>>(
            X, Hs, Wxb, Whb, C, bx, bh, out);
    } else {
        dim3 grid(BATCH / BM, HD / BNH);
        lstm_fused_f32<<<grid, 256, 0, stream>>>(X, Hs, C, Wx, Wh, bx, bh, out);
    }
}

// Round 9
// 332.726 us; speedup vs baseline: 1.2689x; 1.0568x over previous
//
#include <hip/hip_runtime.h>
#include <stdint.h>

// LSTMCell: B=8192, I=H=1024, fp32 in/out.
// Round 9: resubmit round-8 anti-phase schedule (round-8 bench was an infra
// failure; audit found no deadlock: barrier parity 97/97, vmcnt invariant
// holds, per-group hazards verified). One hardening change: barriers are
// __builtin_amdgcn_s_barrier() (the r2-r6-proven form) instead of raw asm.
// Groups: wm=0 waves run R5 quad order, wm=1 waves a one-quad-rotated
// (MFMA-first) order, so each SIMD (wave w -> SIMD w&3) has one wave of
// each group: one MFMAs while the other ds_reads.
#define BATCH 8192
#define HD    1024
#define NT    32      // K-tiles of 64: 16 for X*Wx^T + 16 for H*Wh^T
// fallback kernel geometry (unchanged, proven)
#define BM    128
#define BNH   32
#define BK    32

typedef __bf16 bf16;
typedef __bf16 bf16x8  __attribute__((ext_vector_type(8)));
typedef __bf16 bf16x4  __attribute__((ext_vector_type(4)));
typedef __bf16 bf16x16 __attribute__((ext_vector_type(16)));
typedef float  f32x4   __attribute__((ext_vector_type(4)));

__device__ __forceinline__ float sigm(float x) {
    return 1.0f / (1.0f + __expf(-x));
}
__device__ __forceinline__ float tanh_f(float x) {
    return 1.0f - 2.0f / (__expf(2.0f * x) + 1.0f);
}
__device__ __forceinline__ bf16x4 cvt4(float4 v) {
    bf16x4 r;
    r[0] = (bf16)v.x; r[1] = (bf16)v.y; r[2] = (bf16)v.z; r[3] = (bf16)v.w;
    return r;
}
// async global->LDS, 16B/lane; LDS dest = wave-uniform base + lane*16.
__device__ __forceinline__ void async_ld16(const void* g, void* l) {
    __builtin_amdgcn_global_load_lds(
        (const __attribute__((address_space(1))) uint32_t*)g,
        (__attribute__((address_space(3))) uint32_t*)l,
        16, 0, 0);
}

// ---- prepass: fp32 -> bf16 for X, H, Wx, Wh into ws (32B stores) ----------
__global__ __launch_bounds__(256) void cvt_prepass(
    const float4* __restrict__ X, const float4* __restrict__ H,
    const float4* __restrict__ Wx, const float4* __restrict__ Wh,
    bf16x16* __restrict__ ws)
{
    const size_t NX = (size_t)BATCH * HD / 16;
    const size_t NW = (size_t)4 * HD * HD / 16;
    const size_t total = 2 * NX + 2 * NW;
    const size_t stride = (size_t)gridDim.x * blockDim.x;
    for (size_t p = (size_t)blockIdx.x * blockDim.x + threadIdx.x;
         p < total; p += stride) {
        const float4* s; size_t o;
        if (p < NX)                { s = X;  o = p; }
        else if (p < 2 * NX)       { s = H;  o = p - NX; }
        else if (p < 2 * NX + NW)  { s = Wx; o = p - 2 * NX; }
        else                       { s = Wh; o = p - 2 * NX - NW; }
        const float4 v0 = s[4 * o + 0], v1 = s[4 * o + 1];
        const float4 v2 = s[4 * o + 2], v3 = s[4 * o + 3];
        bf16x16 r;
        r[0]  = (bf16)v0.x; r[1]  = (bf16)v0.y; r[2]  = (bf16)v0.z; r[3]  = (bf16)v0.w;
        r[4]  = (bf16)v1.x; r[5]  = (bf16)v1.y; r[6]  = (bf16)v1.z; r[7]  = (bf16)v1.w;
        r[8]  = (bf16)v2.x; r[9]  = (bf16)v2.y; r[10] = (bf16)v2.z; r[11] = (bf16)v2.w;
        r[12] = (bf16)v3.x; r[13] = (bf16)v3.y; r[14] = (bf16)v3.z; r[15] = (bf16)v3.w;
        ws[p] = r;
    }
}

// ---- main: 256x256 tile, BK=64, 8 waves, anti-phase 3-barrier schedule ----
// Staging/vmcnt = R5: prologue A(0),B(0),B(1),A(1)lo; per tile A(t+1)hi@R1,
// B(t+2)lo@R2, B(t+2)hi+A(t+2)lo@R3, one vmcnt(6)/tile.
// Barrier #1: both groups' B(t)-lo reads done -> B-lo(t+2) stage safe.
// Barrier #2: both groups' A(t)/B(t)-hi reads done -> stages safe.
// Barrier #3: after vmcnt(6) -> buf(t+1) published.
// g0: [rd bF23; Q00; Q02; rd aF47] |#1 Q42 |#2 |#3 Q40; trail aF03+bF01(t+1)
// g1: [Q42; rd bF01; Q40; rd aF03] |#1 Q00 |#2 |#3 Q02; trail aF47+bF23(t+1)

#define BARM() __builtin_amdgcn_s_barrier()

#define STAGE_A(tn_, hf_, o0_, o1_) do {                                    \
    const char* s_ = ((tn_) < 16) ? XbC : HbC;                              \
    const int kt_ = ((tn_) & 15) << 7;                                      \
    char* d_ = lds + (((tn_) & 1) << 16) + (hf_) * 16384 + tid16;           \
    async_ld16(s_ + (o0_) + kt_, d_);                                       \
    async_ld16(s_ + (o1_) + kt_, d_ + 8192); } while (0)

#define STAGE_B(tn_, hf_, o0_, o1_) do {                                    \
    const char* s_ = ((tn_) < 16) ? WxC : WhC;                              \
    const int kt_ = ((tn_) & 15) << 7;                                      \
    char* d_ = lds + (((tn_) & 1) << 16) + 32768 + (hf_) * 16384 + tid16;   \
    async_ld16(s_ + (o0_) + kt_, d_);                                       \
    async_ld16(s_ + (o1_) + kt_, d_ + 8192); } while (0)

#define MFMA_Q(IMB_, INB_)                                                  \
    _Pragma("unroll")                                                       \
    for (int im_ = 0; im_ < 4; ++im_) {                                     \
        _Pragma("unroll")                                                   \
        for (int in_ = 0; in_ < 2; ++in_) {                                 \
            acc[im_ + IMB_][in_ + INB_] =                                   \
                __builtin_amdgcn_mfma_f32_16x16x32_bf16(aF[im_][0],         \
                    bF[in_ + INB_][0], acc[im_ + IMB_][in_ + INB_], 0,0,0); \
            acc[im_ + IMB_][in_ + INB_] =                                   \
                __builtin_amdgcn_mfma_f32_16x16x32_bf16(aF[im_][1],         \
                    bF[in_ + INB_][1], acc[im_ + IMB_][in_ + INB_], 0,0,0); \
        }                                                                   \
    }

#define RD_A(L_, off_) do {                                                 \
    _Pragma("unroll")                                                       \
    for (int im_ = 0; im_ < 4; ++im_) {                                     \
        aF[im_][0] = *(const bf16x8*)((L_) + (im_ + (off_)) * 2048 + sw0);  \
        aF[im_][1] = *(const bf16x8*)((L_) + (im_ + (off_)) * 2048 + sw1);  \
    } } while (0)

#define RD_B(in0_, L_) do {                                                 \
    _Pragma("unroll")                                                       \
    for (int in_ = (in0_); in_ < (in0_) + 2; ++in_) {                       \
        bF[in_][0] = *(const bf16x8*)((L_) + in_ * 2048 + sw0);             \
        bF[in_][1] = *(const bf16x8*)((L_) + in_ * 2048 + sw1);             \
    } } while (0)

#define SP1() __builtin_amdgcn_s_setprio(1)
#define SP0() __builtin_amdgcn_s_setprio(0)

__global__ __launch_bounds__(512, 2) void lstm_mfma8(
    const bf16* __restrict__ Xb, const bf16* __restrict__ Hb,
    const bf16* __restrict__ Wxb, const bf16* __restrict__ Whb,
    const float* __restrict__ C, const float* __restrict__ bx,
    const float* __restrict__ bh, float* __restrict__ out)
{
    __shared__ __align__(16) char lds[131072];

    const int tid  = threadIdx.x;
    const int lane = tid & 63;
    const int w    = tid >> 6;
    const int wm   = w >> 2;            // group: M half 0/1
    const int wn   = w & 3;             // N quarter 0..3
    const int quad = lane >> 4;
    const int c16  = lane & 15;

    // XCD k owns M-tiles {4k..4k+3} x all 16 N-cols (N-minor), bijective.
    const int bid = blockIdx.x;
    const int k8  = bid & 7;
    const int j   = bid >> 3;
    const int mi  = (k8 << 2) | (j & 3);
    const int col = j >> 2;
    const int m0  = mi << 8;
    const int h0  = col << 6;

    // ---- staging addresses (pre-swizzled global source, linear LDS dest) --
    const int tid16 = tid << 4;
    const int R0    = tid >> 3;
    const uint32_t swc = ((tid & 7) ^ (R0 & 7)) << 4;
    const char* XbC = (const char*)Xb;
    const char* HbC = (const char*)Hb;
    const char* WxC = (const char*)Wxb;
    const char* WhC = (const char*)Whb;
    const uint32_t a00 = ((uint32_t)(m0 + R0)       << 11) + swc;
    const uint32_t a01 = ((uint32_t)(m0 + R0 +  64) << 11) + swc;
    const uint32_t a10 = ((uint32_t)(m0 + R0 + 128) << 11) + swc;
    const uint32_t a11 = ((uint32_t)(m0 + R0 + 192) << 11) + swc;
#define NROW(r_) (((((r_) >> 4) & 3) << 10) + h0 + (((r_) >> 6) << 4) + ((r_) & 15))
    const uint32_t b00 = ((uint32_t)NROW(R0)       << 11) + swc;
    const uint32_t b01 = ((uint32_t)NROW(R0 +  64) << 11) + swc;
    const uint32_t b10 = ((uint32_t)NROW(R0 + 128) << 11) + swc;
    const uint32_t b11 = ((uint32_t)NROW(R0 + 192) << 11) + swc;
#undef NROW

    // ---- ds_read bases (swizzled col16: row&7 == c16&7 for all frags) -----
    const int baseA = (wm * 128 + c16) * 128;
    const int baseB = 32768 + (wn * 64 + c16) * 128;
    const int sw0 = ((quad    ) ^ (c16 & 7)) << 4;
    const int sw1 = ((quad + 4) ^ (c16 & 7)) << 4;

    f32x4 acc[8][4];
#pragma unroll
    for (int i = 0; i < 8; ++i)
#pragma unroll
        for (int j2 = 0; j2 < 4; ++j2) acc[i][j2] = (f32x4){0.f, 0.f, 0.f, 0.f};

    // ---- prologue: A(0), B(0), B(1), A(1)-lo; drain tile0, leave 6 --------
    STAGE_A(0, 0, a00, a01);
    STAGE_A(0, 1, a10, a11);
    STAGE_B(0, 0, b00, b01);
    STAGE_B(0, 1, b10, b11);
    STAGE_B(1, 0, b00, b01);
    STAGE_B(1, 1, b10, b11);
    STAGE_A(1, 0, a00, a01);
    asm volatile("s_waitcnt vmcnt(6)" ::: "memory");
    BARM();

    bf16x8 aF[4][2], bF[4][2];
    {
        const char* LA0 = lds + baseA;
        const char* LB0 = lds + baseB;
        if (wm == 0) { RD_A(LA0, 0); RD_B(0, LB0); }   // aF03, bF01
        else         { RD_A(LA0, 4); RD_B(2, LB0); }   // aF47, bF23
    }

    if (wm == 0) {
        // ---- group 0: R5 order ------------------------------------------
#pragma unroll 1
        for (int t = 0; t < NT; ++t) {
            const char* LA  = lds + ((t & 1) << 16) + baseA;
            const char* LB  = lds + ((t & 1) << 16) + baseB;
            const char* LAn = lds + (((t + 1) & 1) << 16) + baseA;
            const char* LBn = lds + (((t + 1) & 1) << 16) + baseB;
            if (t + 1 < NT) STAGE_A(t + 1, 1, a10, a11);
            RD_B(2, LB);                       // bF23(t)
            SP1(); MFMA_Q(0, 0); SP0();
            SP1(); MFMA_Q(0, 2); SP0();
            RD_A(LA, 4);                       // aF <- im4-7(t)
            BARM();  // #1
            if (t + 2 < NT) STAGE_B(t + 2, 0, b00, b01);
            SP1(); MFMA_Q(4, 2); SP0();
            BARM();  // #2
            if (t + 2 < NT) {
                STAGE_B(t + 2, 1, b10, b11);
                STAGE_A(t + 2, 0, a00, a01);
                asm volatile("s_waitcnt vmcnt(6)" ::: "memory");
            } else if (t == NT - 2) {
                asm volatile("s_waitcnt vmcnt(0)" ::: "memory");
            }
            BARM();  // #3
            SP1(); MFMA_Q(4, 0); SP0();
            if (t + 1 < NT) {
                RD_A(LAn, 0);                  // aF03(t+1)
                RD_B(0, LBn);                  // bF01(t+1)
            }
        }
    } else {
        // ---- group 1: one-quad-rotated (MFMA-first) ---------------------
#pragma unroll 1
        for (int t = 0; t < NT; ++t) {
            const char* LA  = lds + ((t & 1) << 16) + baseA;
            const char* LB  = lds + ((t & 1) << 16) + baseB;
            const char* LAn = lds + (((t + 1) & 1) << 16) + baseA;
            const char* LBn = lds + (((t + 1) & 1) << 16) + baseB;
            if (t + 1 < NT) STAGE_A(t + 1, 1, a10, a11);
            SP1(); MFMA_Q(4, 2); SP0();        // aF47(t)+bF23(t) preloaded
            RD_B(0, LB);                       // bF01(t)
            SP1(); MFMA_Q(4, 0); SP0();        // aF47+bF01
            RD_A(LA, 0);                       // aF <- im0-3(t)
            BARM();  // #1
            if (t + 2 < NT) STAGE_B(t + 2, 0, b00, b01);
            SP1(); MFMA_Q(0, 0); SP0();        // aF03+bF01
            BARM();  // #2
            if (t + 2 < NT) {
                STAGE_B(t + 2, 1, b10, b11);
                STAGE_A(t + 2, 0, a00, a01);
                asm volatile("s_waitcnt vmcnt(6)" ::: "memory");
            } else if (t == NT - 2) {
                asm volatile("s_waitcnt vmcnt(0)" ::: "memory");
            }
            BARM();  // #3
            SP1(); MFMA_Q(0, 2); SP0();        // aF03+bF23(t)
            if (t + 1 < NT) {
                RD_A(LAn, 4);                  // aF47(t+1)
                RD_B(2, LBn);                  // bF23(t+1)
            }
        }
    }

    // ---- fused LSTM epilogue: lane holds all 4 gates of (m-range, h) ------
    const int h = h0 + wn * 16 + c16;
    float bias[4];
#pragma unroll
    for (int g = 0; g < 4; ++g) bias[g] = bx[g * HD + h] + bh[g * HD + h];
    const size_t BH = (size_t)BATCH * HD;
    const int mb = m0 + wm * 128 + quad * 4;
#pragma unroll
    for (int im = 0; im < 8; ++im) {
#pragma unroll
        for (int r = 0; r < 4; ++r) {
            const int m = mb + im * 16 + r;
            const float gi = acc[im][0][r] + bias[0];
            const float gf = acc[im][1][r] + bias[1];
            const float gg = acc[im][2][r] + bias[2];
            const float go = acc[im][3][r] + bias[3];
            const float ia = sigm(gi);
            const float fa = sigm(gf);
            const float ga = tanh_f(gg);
            const float oa = sigm(go);
            const size_t idx = (size_t)m * HD + h;
            const float nc = fmaf(fa, C[idx], ia * ga);
            const float nh = oa * tanh_f(nc);
            out[idx]          = nh;
            out[BH + idx]     = nh;
            out[2 * BH + idx] = nc;
        }
    }
}

// ---- fallback (proven): fp32 loads + in-loop cvt, register staging --------
__global__ __launch_bounds__(256) void lstm_fused_f32(
    const float* __restrict__ X, const float* __restrict__ Hs,
    const float* __restrict__ C, const float* __restrict__ Wx,
    const float* __restrict__ Wh, const float* __restrict__ bx,
    const float* __restrict__ bh, float* __restrict__ out)
{
    __shared__ __align__(16) bf16 As[BM * BK];
    __shared__ __align__(16) bf16 Bs[BM * BK];
    const int tid = threadIdx.x, lane = tid & 63, w = tid >> 6;
    const int m0 = blockIdx.x * BM, h0 = blockIdx.y * BNH;
    f32x4 acc[2][8];
#pragma unroll
    for (int i = 0; i < 2; ++i)
#pragma unroll
        for (int j = 0; j < 8; ++j) acc[i][j] = (f32x4){0.f, 0.f, 0.f, 0.f};
    int arow[4], col4[4], bn[4];
#pragma unroll
    for (int j = 0; j < 4; ++j) {
        const int off = tid * 16 + j * 4096;
        arow[j] = off >> 7;
        col4[j] = (off & 127) >> 2;
        bn[j]   = ((arow[j] >> 5) << 10) + h0 + (arow[j] & 31);
    }
    const int quad = lane >> 4, c16 = lane & 15;
    float4 pA[4], pB[4];
    auto loadi = [&](int i) {
        const float* Ab = (i < 32) ? X : Hs;
        const float* Wb = (i < 32) ? Wx : Wh;
        const int kin = (i & 31) << 5;
#pragma unroll
        for (int j = 0; j < 4; ++j) {
            pA[j] = *(const float4*)(Ab + (size_t)(m0 + arow[j]) * HD + kin + col4[j]);
            pB[j] = *(const float4*)(Wb + (size_t)bn[j] * HD + kin + col4[j]);
        }
    };
    loadi(0);
#pragma unroll 1
    for (int i = 0; i < 64; ++i) {
        __syncthreads();
#pragma unroll
        for (int j = 0; j < 4; ++j) {
            *(bf16x4*)&As[arow[j] * BK + col4[j]] = cvt4(pA[j]);
            *(bf16x4*)&Bs[arow[j] * BK + col4[j]] = cvt4(pB[j]);
        }
        __syncthreads();
        if (i < 63) loadi(i + 1);
        bf16x8 a[2], b[8];
#pragma unroll
        for (int im = 0; im < 2; ++im)
            a[im] = *(const bf16x8*)((const char*)As + (w * 32 + im * 16 + c16) * 64 + quad * 16);
#pragma unroll
        for (int in = 0; in < 8; ++in)
            b[in] = *(const bf16x8*)((const char*)Bs + (in * 16 + c16) * 64 + quad * 16);
#pragma unroll
        for (int im = 0; im < 2; ++im)
#pragma unroll
            for (int in = 0; in < 8; ++in)
                acc[im][in] = __builtin_amdgcn_mfma_f32_16x16x32_bf16(
                    a[im], b[in], acc[im][in], 0, 0, 0);
    }
    float bias[2][4];
#pragma unroll
    for (int hs = 0; hs < 2; ++hs) {
        const int h = h0 + hs * 16 + c16;
#pragma unroll
        for (int g = 0; g < 4; ++g) bias[hs][g] = bx[g * HD + h] + bh[g * HD + h];
    }
    const size_t BH = (size_t)BATCH * HD;
#pragma unroll
    for (int im = 0; im < 2; ++im)
#pragma unroll
        for (int r = 0; r < 4; ++r) {
            const int m = m0 + w * 32 + im * 16 + quad * 4 + r;
#pragma unroll
            for (int hs = 0; hs < 2; ++hs) {
                const int h = h0 + hs * 16 + c16;
                const float gi = acc[im][hs + 0][r] + bias[hs][0];
                const float gf = acc[im][hs + 2][r] + bias[hs][1];
                const float gg = acc[im][hs + 4][r] + bias[hs][2];
                const float go = acc[im][hs + 6][r] + bias[hs][3];
                const float ia = sigm(gi), fa = sigm(gf);
                const float ga = tanh_f(gg), oa = sigm(go);
                const size_t idx = (size_t)m * HD + h;
                const float nc = fa * C[idx] + ia * ga;
                const float nh = oa * tanh_f(nc);
                out[idx] = nh; out[BH + idx] = nh; out[2 * BH + idx] = nc;
            }
        }
}

extern "C" void kernel_launch(void* const* d_in, const int* in_sizes, int n_in,
                              void* d_out, int out_size, void* d_ws, size_t ws_size,
                              hipStream_t stream) {
    const float* X  = (const float*)d_in[0];
    const float* Hs = (const float*)d_in[1];
    const float* C  = (const float*)d_in[2];
    const float* Wx = (const float*)d_in[3];
    const float* Wh = (const float*)d_in[4];
    const float* bx = (const float*)d_in[5];
    const float* bh = (const float*)d_in[6];
    float* out = (float*)d_out;

    const size_t need = 48ull << 20;  // Xb+Hb (32MB) + Wxb+Whb (16MB)
    if (ws_size >= need) {
        bf16* Xb  = (bf16*)d_ws;
        bf16* Hb  = Xb + (size_t)BATCH * HD;
        bf16* Wxb = Hb + (size_t)BATCH * HD;
        bf16* Whb = Wxb + (size_t)4 * HD * HD;
        cvt_prepass<<<4096, 256, 0, stream>>>(
            (const float4*)X, (const float4*)Hs,
            (const float4*)Wx, (const float4*)Wh, (bf16x16*)d_ws);
        lstm_mfma8<<<dim3(512), dim3(512), 0, stream>>>(
            Xb, Hb, Wxb, Whb, C, bx, bh, out);
    } else {
        dim3 grid(BATCH / BM, HD / BNH);
        lstm_fused_f32<<<grid, 256, 0, stream>>>(X, Hs, C, Wx, Wh, bx, bh, out);
    }
}